// Round 14
// baseline (2010.303 us; speedup 1.0000x reference)
//
#include <hip/hip_runtime.h>

#define TT 2048
#define NB 512

typedef float v2f __attribute__((ext_vector_type(2)));

__device__ __forceinline__ v2f mk2(float a, float b) { v2f r; r.x = a; r.y = b; return r; }
__device__ __forceinline__ float rcpf(float x) { return __builtin_amdgcn_rcpf(x); }
__device__ __forceinline__ float fsig(float x) { return rcpf(1.0f + __expf(-x)); }
__device__ __forceinline__ float ftanh(float x) {
    return fmaf(2.0f, rcpf(1.0f + __expf(-2.0f * x)), -1.0f);
}

template<int C>
__device__ __forceinline__ float dppmov(float s) {
    return __int_as_float(__builtin_amdgcn_update_dpp(
        __float_as_int(s), __float_as_int(s), C, 0xF, 0xF, false));
}
// Full wave64 sum, result in lane 63 (verified R6-R13).
__device__ __forceinline__ float wave_sum63(float s) {
    s += dppmov<0x111>(s); s += dppmov<0x112>(s); s += dppmov<0x114>(s);
    s += dppmov<0x118>(s); s += dppmov<0x142>(s); s += dppmov<0x143>(s);
    return s;
}
template<int Q>
__device__ __forceinline__ float qbcast(float x) {
    return __int_as_float(__builtin_amdgcn_update_dpp(
        __float_as_int(x), __float_as_int(x), Q * 0x55, 0xF, 0xF, false));
}
// row_ror:K (K=1..15): dst lane p <- src lane (p-K)&15 within each 16-row.
// Same direction family as the R10-VERIFIED row_shr (i <- i-N), with wrap.
template<int K>
__device__ __forceinline__ float rotk(float v) {
    if constexpr (K == 0) return v;
    else return dppmov<0x120 + K>(v);
}

// ============ Kernel 1: layer 1 + zp partials (rotation matvec) ============
// 512 blocks x 4 waves, 1 elem/block, 2 blocks/CU = 2 waves/SIMD.
// Quad-gate layout (R6): lane = 4u'+g, unit = wave*16+u', col = g*64+unit.
// h-broadcast via 4 STRIDED ds_read_b32 (64 unique floats per op; words
// 0..63 -> 2 lanes/bank = free) + 15 inline row_ror DPP variants per read:
// breaks the uniform-read invariant (64 b128 ops/elem/step -> ~22 LDS ops)
// that walled R6/R11/R13 at ~1600 cyc/step on the single per-CU LDS pipe.
// Weight order per lane permuted at load to match the rotation:
//   w[r][k] = W1[1 + 16*((row+r)&3) + ((pos-k)&15)][col].
// Gate exchange: qbcast (VALU). ONE barrier/step. Layer-2 partial reuses the
// r=0 read (= h[lane]); zpr ring flushed to global every 16 steps.
__global__ __launch_bounds__(256)
__attribute__((amdgpu_waves_per_eu(2, 2)))
void lstm1_kernel(const float* __restrict__ x,
                  const float* __restrict__ W1,
                  const float* __restrict__ b1,
                  const float* __restrict__ W2,
                  float* __restrict__ zout)
{
    __shared__ __align__(16) float xall[TT + 4];
    __shared__ __align__(16) float h1row[2][64];   // parity-dbuf h1
    __shared__ __align__(16) float zpr[32][4];     // layer-2 partial ring

    const int tid  = threadIdx.x;
    const int wave = tid >> 6;
    const int lane = tid & 63;
    const int b    = blockIdx.x;

    for (int i = tid; i < TT; i += 256) xall[i] = x[b * TT + i];
    if (tid < 4) xall[TT + tid] = 0.0f;

    const int g    = lane & 3;           // gate i,j,f,o
    const int up   = lane >> 2;          // unit-in-wave 0..15
    const int unit = (wave << 4) + up;   // global unit 0..63
    const int col  = (g << 6) + unit;    // W1 (65,256) column
    const int row4 = lane >> 4;          // DPP row 0..3
    const int pos  = lane & 15;          // position within DPP row

    // 64 named weights, permuted to the rotation consumption order.
#define MI(r, k) (16 * (((row4) + (r)) & 3) + (((pos) - (k)) & 15))
#define DW(r, k) const float w_##r##_##k = W1[(1 + MI(r, k)) * 256 + col];
#define DWROW(r) DW(r,0) DW(r,1) DW(r,2)  DW(r,3)  DW(r,4)  DW(r,5)  DW(r,6)  DW(r,7) \
                 DW(r,8) DW(r,9) DW(r,10) DW(r,11) DW(r,12) DW(r,13) DW(r,14) DW(r,15)
    DWROW(0) DWROW(1) DWROW(2) DWROW(3)
#undef DWROW
#undef DW

    // strided-read addresses for row-groups 1..3 (group 0 address == lane)
    const int a1 = 16 * ((row4 + 1) & 3) + pos;
    const int a2 = 16 * ((row4 + 2) & 3) + pos;
    const int a3 = 16 * ((row4 + 3) & 3) + pos;

    const float w0x   = W1[col];
    const float biasF = b1[col] + ((g == 2) ? 1.0f : 0.0f);
    const float nlm   = (g == 1) ? -2.0f : -1.0f;
    const bool  isj   = (g == 1);

    const float w2g = W2[lane * 4 + wave];   // layer-2 h-part, gate = wave

    float c1 = 0.0f;                         // redundant per quad

    if (tid < 64) h1row[0][tid] = 0.0f;
    __syncthreads();

    float* __restrict__ zb = zout + (size_t)b * TT * 4;

#define FK(r, k) acc##r = fmaf(rotk<k>(v##r), w_##r##_##k, acc##r);
#define FROW(r) FK(r,0) FK(r,1) FK(r,2)  FK(r,3)  FK(r,4)  FK(r,5)  FK(r,6)  FK(r,7) \
                FK(r,8) FK(r,9) FK(r,10) FK(r,11) FK(r,12) FK(r,13) FK(r,14) FK(r,15)

#define STEP(P, t, xv)                                                        \
    {                                                                         \
        float v0 = 0.0f;                                                      \
        if ((t) <= TT) v0 = h1row[P][lane];    /* = h[lane], reused below */  \
        if ((t) < TT) {                                                       \
            const float v1 = h1row[P][a1];                                    \
            const float v2 = h1row[P][a2];                                    \
            const float v3 = h1row[P][a3];                                    \
            float acc0 = fmaf((xv), w0x, biasF);                              \
            float acc1 = 0.f, acc2 = 0.f, acc3 = 0.f;                         \
            FROW(0) FROW(1) FROW(2) FROW(3)                                   \
            const float zfull = (acc0 + acc1) + (acc2 + acc3);                \
            const float e = __expf(zfull * nlm);                              \
            const float r = rcpf(1.0f + e);                                   \
            const float v = isj ? fmaf(2.0f, r, -1.0f) : r;                   \
            const float gi = qbcast<0>(v), gj = qbcast<1>(v);                 \
            const float gf = qbcast<2>(v), go = qbcast<3>(v);                 \
            c1 = fmaf(c1, gf, gi * gj);                                       \
            const float h1v = ftanh(c1) * go;                                 \
            if (g == 0) h1row[(P) ^ 1][unit] = h1v;                           \
        }                                                                     \
        if ((t) >= 1 && (t) <= TT) {   /* layer-2 partial for step t-1 */     \
            const float s = wave_sum63(v0 * w2g);                             \
            if (lane == 63) zpr[((t) - 1) & 31][wave] = s;                    \
        }                                                                     \
        __syncthreads();               /* the ONLY barrier per step */        \
        if ((t) >= 16 && (t) <= TT && ((t) & 15) == 0 &&                      \
            wave == (((t) >> 4) & 3)) {                                       \
            const int base = (t) - 16;                                        \
            const float zv = ((const float*)zpr)[((base & 31) << 2) + lane];  \
            zb[(size_t)(base << 2) + lane] = zv;                              \
        }                                                                     \
    }

    for (int it = 0; it <= TT; it += 2) {
        const float2 x2 = *(const float2*)&xall[it];
        STEP(0, it,     x2.x)
        STEP(1, it + 1, x2.y)
    }
#undef STEP
#undef FROW
#undef FK
#undef MI
}

// ===================== Kernel 2: layer-2 recurrence (R13, proven) ==========
__global__ __launch_bounds__(64)
void lstm2_chain(const float* __restrict__ zp,
                 const float* __restrict__ W2,
                 const float* __restrict__ b2,
                 float* __restrict__ out)
{
    const int lane = threadIdx.x & 63;
    const int e    = lane >> 2;
    const int g    = lane & 3;
    const int elem = (blockIdx.x << 4) + e;

    const float w2h = W2[256 + g];
    const float bb  = b2[g] + ((g == 2) ? 1.0f : 0.0f);
    const float nlm = (g == 1) ? -2.0f : -1.0f;
    const float k2  = (g == 1) ?  2.0f :  1.0f;
    const float k3  = (g == 1) ? -1.0f :  0.0f;

    const float* __restrict__ zrow = zp + (size_t)elem * TT * 4 + g;
    float* __restrict__ orow = out + (size_t)elem * TT;

    float c2 = 0.0f, h2 = 0.0f;

    float zc[16];
#pragma unroll
    for (int k = 0; k < 16; ++k) zc[k] = zrow[k << 2];

    for (int t0 = 0; t0 < TT; t0 += 16) {
        float zn[16];
        if (t0 + 16 < TT) {
#pragma unroll
            for (int k = 0; k < 16; ++k) zn[k] = zrow[((t0 + 16 + k) << 2)];
        }
        float st0 = 0.f, st1 = 0.f, st2 = 0.f, st3 = 0.f;
#pragma unroll
        for (int k = 0; k < 16; ++k) {
            const float arg = fmaf(w2h, h2, zc[k] + bb);
            const float ev  = __expf(arg * nlm);
            const float rv  = rcpf(1.0f + ev);
            const float v   = fmaf(k2, rv, k3);
            const float vi = qbcast<0>(v), vj = qbcast<1>(v);
            const float vf = qbcast<2>(v), vo = qbcast<3>(v);
            c2 = fmaf(c2, vf, vi * vj);
            h2 = ftanh(c2) * vo;
            const bool mine = (g == (k & 3));
            if ((k >> 2) == 0) st0 = mine ? h2 : st0;
            else if ((k >> 2) == 1) st1 = mine ? h2 : st1;
            else if ((k >> 2) == 2) st2 = mine ? h2 : st2;
            else st3 = mine ? h2 : st3;
        }
        orow[t0 + g]      = st0;
        orow[t0 + 4 + g]  = st1;
        orow[t0 + 8 + g]  = st2;
        orow[t0 + 12 + g] = st3;
#pragma unroll
        for (int k = 0; k < 16; ++k) zc[k] = zn[k];
    }
}

// ===================== Fallback: R11 monolithic (proven) ==================
__global__ __launch_bounds__(512)
__attribute__((amdgpu_waves_per_eu(4, 4)))
void lstm2_mono(const float* __restrict__ x,
                const float* __restrict__ W1,
                const float* __restrict__ b1,
                const float* __restrict__ W2,
                const float* __restrict__ b2,
                float* __restrict__ out)
{
    __shared__ __align__(16) float xall[TT + 4];
    __shared__ __align__(16) float h1x[2][80];
    __shared__ __align__(16) float zpq[4][4];
    __shared__ __align__(16) float h2buf[2][64];

    const int tid  = threadIdx.x;
    const int wave = tid >> 6;
    const int lane = tid & 63;
    const int b    = blockIdx.x;

    for (int i = tid; i < TT; i += 512) xall[i] = x[b * TT + i];
    if (tid < 4) xall[TT + tid] = 0.0f;

    const int u    = lane >> 3;
    const int h    = (lane >> 2) & 1;
    const int g    = lane & 3;
    const int unit = (wave << 3) + u;
    const int col  = (g << 6) + unit;

#define DECLW(k) const v2f wp##k = mk2(W1[(1 + 32*h + 2*(k)) * 256 + col], \
                                       W1[(2 + 32*h + 2*(k)) * 256 + col]);
    DECLW(0)  DECLW(1)  DECLW(2)  DECLW(3)
    DECLW(4)  DECLW(5)  DECLW(6)  DECLW(7)
    DECLW(8)  DECLW(9)  DECLW(10) DECLW(11)
    DECLW(12) DECLW(13) DECLW(14) DECLW(15)
#undef DECLW

    const float w0x   = (h == 0) ? W1[col] : 0.0f;
    const float biasF = (h == 0) ? (b1[col] + ((g == 2) ? 1.0f : 0.0f)) : 0.0f;
    const float nlm   = (g == 1) ? -2.0f : -1.0f;
    const bool  isj   = (g == 1);

    const float w2g  = W2[lane * 4 + (wave & 3)];
    const float w2h0 = W2[256], w2h1 = W2[257], w2h2 = W2[258], w2h3 = W2[259];
    const float b20 = b2[0], b21 = b2[1], b22 = b2[2], b23 = b2[3];

    float c1 = 0.0f;
    float c2 = 0.0f, h2v = 0.0f;

    const int hbase = h * 48;
    const int ridx  = lane + ((lane >> 5) << 4);
    const int widx  = (unit < 32) ? unit : unit + 16;

    if (tid < 160) ((float*)h1x)[tid] = 0.0f;
    __syncthreads();

    float* __restrict__ outb = out + b * TT;

#define STEP(P, t, xv)                                                        \
    {                                                                         \
        if ((t) < TT) {                                                       \
            const float4* hp = (const float4*)&h1x[P][hbase];                 \
            const float4 q0 = hp[0], q1 = hp[1], q2 = hp[2], q3 = hp[3];      \
            const float4 q4 = hp[4], q5 = hp[5], q6 = hp[6], q7 = hp[7];      \
            v2f a0 = mk2(fmaf((xv), w0x, biasF), 0.0f);                       \
            v2f a1 = mk2(0.f, 0.f), a2 = mk2(0.f, 0.f), a3 = mk2(0.f, 0.f);  \
            a0 = __builtin_elementwise_fma(mk2(q0.x, q0.y), wp0,  a0);        \
            a1 = __builtin_elementwise_fma(mk2(q0.z, q0.w), wp1,  a1);        \
            a2 = __builtin_elementwise_fma(mk2(q1.x, q1.y), wp2,  a2);        \
            a3 = __builtin_elementwise_fma(mk2(q1.z, q1.w), wp3,  a3);        \
            a0 = __builtin_elementwise_fma(mk2(q2.x, q2.y), wp4,  a0);        \
            a1 = __builtin_elementwise_fma(mk2(q2.z, q2.w), wp5,  a1);        \
            a2 = __builtin_elementwise_fma(mk2(q3.x, q3.y), wp6,  a2);        \
            a3 = __builtin_elementwise_fma(mk2(q3.z, q3.w), wp7,  a3);        \
            a0 = __builtin_elementwise_fma(mk2(q4.x, q4.y), wp8,  a0);        \
            a1 = __builtin_elementwise_fma(mk2(q4.z, q4.w), wp9,  a1);        \
            a2 = __builtin_elementwise_fma(mk2(q5.x, q5.y), wp10, a2);        \
            a3 = __builtin_elementwise_fma(mk2(q5.z, q5.w), wp11, a3);        \
            a0 = __builtin_elementwise_fma(mk2(q6.x, q6.y), wp12, a0);        \
            a1 = __builtin_elementwise_fma(mk2(q6.z, q6.w), wp13, a1);        \
            a2 = __builtin_elementwise_fma(mk2(q7.x, q7.y), wp14, a2);        \
            a3 = __builtin_elementwise_fma(mk2(q7.z, q7.w), wp15, a3);        \
            const v2f sv = (a0 + a1) + (a2 + a3);                             \
            const float zh = sv.x + sv.y;                                     \
            const float tshr = dppmov<0x114>(zh);                             \
            const float tshl = dppmov<0x104>(zh);                             \
            const float zfull = zh + (h ? tshr : tshl);                       \
            const float e = __expf(zfull * nlm);                              \
            const float r = rcpf(1.0f + e);                                   \
            const float v = isj ? fmaf(2.0f, r, -1.0f) : r;                   \
            const float gi = qbcast<0>(v), gj = qbcast<1>(v);                 \
            const float gf = qbcast<2>(v), go = qbcast<3>(v);                 \
            c1 = fmaf(c1, gf, gi * gj);                                       \
            const float h1v = ftanh(c1) * go;                                 \
            if ((lane & 7) == 0) h1x[(P) ^ 1][widx] = h1v;                    \
        }                                                                     \
        if (wave < 4 && (t) >= 1 && (t) <= TT) {                              \
            const float s = wave_sum63(h1x[P][ridx] * w2g);                   \
            if (lane == 63) zpq[((t) - 1) & 3][wave] = s;                     \
        }                                                                     \
        if (wave == 7 && lane == 0 && (t) >= 2 && (t) <= TT + 1) {            \
            const int st = (t) - 2;                                           \
            const float4 z4 = *(const float4*)zpq[st & 3];                    \
            const float zi = z4.x + fmaf(h2v, w2h0, b20);                     \
            const float zj = z4.y + fmaf(h2v, w2h1, b21);                     \
            const float zf = z4.z + fmaf(h2v, w2h2, b22);                     \
            const float zo = z4.w + fmaf(h2v, w2h3, b23);                     \
            c2 = c2 * fsig(zf + 1.0f) + fsig(zi) * ftanh(zj);                 \
            h2v = ftanh(c2) * fsig(zo);                                       \
            h2buf[(st >> 6) & 1][st & 63] = h2v;                              \
        }                                                                     \
        __syncthreads();                                                      \
        if (wave == 4 && (t) >= 66 && ((t) & 63) == 2) {                      \
            const int blk = ((t) - 66) >> 6;                                  \
            outb[(blk << 6) + lane] = h2buf[blk & 1][lane];                   \
        }                                                                     \
    }

    for (int it = 0; it <= TT + 2; it += 2) {
        const float2 x2 = *(const float2*)&xall[it];
        STEP(0, it,     x2.x)
        STEP(1, it + 1, x2.y)
    }
#undef STEP
}

extern "C" void kernel_launch(void* const* d_in, const int* in_sizes, int n_in,
                              void* d_out, int out_size, void* d_ws, size_t ws_size,
                              hipStream_t stream)
{
    const float* x  = (const float*)d_in[0];
    const float* W1 = (const float*)d_in[1];
    const float* b1 = (const float*)d_in[2];
    const float* W2 = (const float*)d_in[3];
    const float* b2 = (const float*)d_in[4];
    float* out = (float*)d_out;

    const size_t need = (size_t)NB * TT * 4 * sizeof(float);   // 16.8 MB
    if (ws_size >= need) {
        float* zp = (float*)d_ws;
        lstm1_kernel<<<NB, 256, 0, stream>>>(x, W1, b1, W2, zp);
        lstm2_chain<<<NB / 16, 64, 0, stream>>>(zp, W2, b2, out);
    } else {
        lstm2_mono<<<NB, 512, 0, stream>>>(x, W1, b1, W2, b2, out);
    }
}

// Round 15
// 1631.458 us; speedup vs baseline: 1.2322x; 1.2322x over previous
//
#include <hip/hip_runtime.h>

#define TT 2048
#define NB 256   // 2 batch elements per block

typedef float v2f __attribute__((ext_vector_type(2)));

__device__ __forceinline__ v2f mk2(float a, float b) { v2f r; r.x = a; r.y = b; return r; }
__device__ __forceinline__ float rcpf(float x) { return __builtin_amdgcn_rcpf(x); }
__device__ __forceinline__ float fsig(float x) { return rcpf(1.0f + __expf(-x)); }
__device__ __forceinline__ float ftanh(float x) {
    return fmaf(2.0f, rcpf(1.0f + __expf(-2.0f * x)), -1.0f);
}

template<int C>
__device__ __forceinline__ float dppmov(float s) {
    return __int_as_float(__builtin_amdgcn_update_dpp(
        __float_as_int(s), __float_as_int(s), C, 0xF, 0xF, false));
}
// Full wave64 sum, result in lane 63 (verified R6-R14).
__device__ __forceinline__ float wave_sum63(float s) {
    s += dppmov<0x111>(s); s += dppmov<0x112>(s); s += dppmov<0x114>(s);
    s += dppmov<0x118>(s); s += dppmov<0x142>(s); s += dppmov<0x143>(s);
    return s;
}
template<int Q>
__device__ __forceinline__ float qbcast(float x) {
    return __int_as_float(__builtin_amdgcn_update_dpp(
        __float_as_int(x), __float_as_int(x), Q * 0x55, 0xF, 0xF, false));
}

// ========== Kernel 1: layer 1 + zp partials, 2 ELEMS PER BLOCK ==========
// 256 blocks x 8 waves (512 thr), 2 blocks/CU -> 16 waves/CU, 4 elems/CU,
// 4 waves/SIMD. Waves 0-3 = elem A, waves 4-7 = elem B; each group is the
// R6-proven quad-gate full-K core: lane = 4u'+g, unit = (wave&3)*16+u',
// 64 named-scalar register weights (R6: VGPR 88 <= 128 budget @ wpe(4,4)),
// qbcast gate exchange (VALU), uniform ds_read_b128 h-broadcast, ONE
// barrier/step shared by both elems. The two elems' dependency chains are
// independent -> co-issue hides each other's lgkm/trans stalls (the R13
// mechanism, now with 2x elems/CU). Layer-2 zp rings per elem, flushed to
// global every 16 steps by a rotating wave of the owning group.
__global__ __launch_bounds__(512)
__attribute__((amdgpu_waves_per_eu(4, 4)))
void lstm1_kernel(const float* __restrict__ x,
                  const float* __restrict__ W1,
                  const float* __restrict__ b1,
                  const float* __restrict__ W2,
                  float* __restrict__ zout)
{
    __shared__ __align__(16) float xall[2][TT + 4];  // per-elem input rows
    __shared__ __align__(16) float h1r[2][2][64];    // [elem][parity][unit]
    __shared__ __align__(16) float zpr[2][32][4];    // [elem][ring][gate]

    const int tid  = threadIdx.x;
    const int wave = tid >> 6;
    const int lane = tid & 63;
    const int b    = blockIdx.x;

    for (int i = tid; i < TT; i += 512) {
        xall[0][i] = x[(2 * b) * TT + i];
        xall[1][i] = x[(2 * b + 1) * TT + i];
    }
    if (tid < 8) xall[tid & 1][TT + (tid >> 1)] = 0.0f;

    const int eid  = wave >> 2;          // 0 = elem A, 1 = elem B
    const int wq   = wave & 3;           // wave-in-group
    const int g    = lane & 3;           // gate i,j,f,o
    const int u    = lane >> 2;          // local unit 0..15
    const int unit = (wq << 4) + u;      // global unit 0..63
    const int col  = (g << 6) + unit;    // W1 (65,256) column

    // 64 named scalar weights (rows 1..64 = h-part), R4/R6-verified residency.
#define DECLW(q) \
    const float wx##q = W1[(4*(q)+1)*256 + col]; \
    const float wy##q = W1[(4*(q)+2)*256 + col]; \
    const float wz##q = W1[(4*(q)+3)*256 + col]; \
    const float ww##q = W1[(4*(q)+4)*256 + col];
    DECLW(0)  DECLW(1)  DECLW(2)  DECLW(3)
    DECLW(4)  DECLW(5)  DECLW(6)  DECLW(7)
    DECLW(8)  DECLW(9)  DECLW(10) DECLW(11)
    DECLW(12) DECLW(13) DECLW(14) DECLW(15)
#undef DECLW

    const float w0x   = W1[col];                              // x-part row 0
    const float biasF = b1[col] + ((g == 2) ? 1.0f : 0.0f);   // fold f-bias
    const float nlm   = (g == 1) ? -2.0f : -1.0f;
    const bool  isj   = (g == 1);

    const float w2g = W2[lane * 4 + wq];     // layer-2 h-part, gate = wq

    float c1 = 0.0f;                         // redundant per quad

    if (tid < 64) { h1r[0][0][tid] = 0.0f; h1r[1][0][tid] = 0.0f; }
    __syncthreads();

    float* __restrict__ zb = zout + (size_t)(2 * b + eid) * TT * 4;
    const float* __restrict__ xrow = xall[eid];

#define FMA4(q) \
    a0 = fmaf(hr[4*(q)+0], wx##q, a0); \
    a1 = fmaf(hr[4*(q)+1], wy##q, a1); \
    a2 = fmaf(hr[4*(q)+2], wz##q, a2); \
    a3 = fmaf(hr[4*(q)+3], ww##q, a3);

#define STEP(P, t, xv)                                                        \
    {                                                                         \
        if ((t) < TT) {                                                       \
            const float* hr = h1r[eid][P];                                    \
            float a0 = fmaf((xv), w0x, biasF);                                \
            float a1 = 0.f, a2 = 0.f, a3 = 0.f;                               \
            FMA4(0)  FMA4(1)  FMA4(2)  FMA4(3)                                \
            FMA4(4)  FMA4(5)  FMA4(6)  FMA4(7)                                \
            FMA4(8)  FMA4(9)  FMA4(10) FMA4(11)                               \
            FMA4(12) FMA4(13) FMA4(14) FMA4(15)                               \
            const float acc = (a0 + a1) + (a2 + a3);                          \
            const float e = __expf(acc * nlm);                                \
            const float r = rcpf(1.0f + e);                                   \
            const float v = isj ? fmaf(2.0f, r, -1.0f) : r;                   \
            const float gi = qbcast<0>(v), gj = qbcast<1>(v);                 \
            const float gf = qbcast<2>(v), go = qbcast<3>(v);                 \
            c1 = fmaf(c1, gf, gi * gj);                                       \
            const float h1v = ftanh(c1) * go;                                 \
            if (g == 0) h1r[eid][(P) ^ 1][unit] = h1v;                        \
        }                                                                     \
        if ((t) >= 1 && (t) <= TT) {   /* layer-2 partial for step t-1 */     \
            const float s = wave_sum63(h1r[eid][P][lane] * w2g);              \
            if (lane == 63) zpr[eid][((t) - 1) & 31][wq] = s;                 \
        }                                                                     \
        __syncthreads();               /* the ONLY barrier per step */        \
        if ((t) >= 16 && (t) <= TT && ((t) & 15) == 0 &&                      \
            wq == (((t) >> 4) & 3)) {                                         \
            const int base = (t) - 16;                                        \
            const float zv = ((const float*)zpr[eid])[((base&31)<<2) + lane]; \
            zb[(size_t)(base << 2) + lane] = zv;                              \
        }                                                                     \
    }

    for (int it = 0; it <= TT; it += 2) {
        const float2 x2 = *(const float2*)&xrow[it];
        STEP(0, it,     x2.x)
        STEP(1, it + 1, x2.y)
    }
#undef STEP
#undef FMA4
}

// ===================== Kernel 2: layer-2 recurrence (R13, proven) ==========
__global__ __launch_bounds__(64)
void lstm2_chain(const float* __restrict__ zp,
                 const float* __restrict__ W2,
                 const float* __restrict__ b2,
                 float* __restrict__ out)
{
    const int lane = threadIdx.x & 63;
    const int e    = lane >> 2;
    const int g    = lane & 3;
    const int elem = (blockIdx.x << 4) + e;

    const float w2h = W2[256 + g];
    const float bb  = b2[g] + ((g == 2) ? 1.0f : 0.0f);
    const float nlm = (g == 1) ? -2.0f : -1.0f;
    const float k2  = (g == 1) ?  2.0f :  1.0f;
    const float k3  = (g == 1) ? -1.0f :  0.0f;

    const float* __restrict__ zrow = zp + (size_t)elem * TT * 4 + g;
    float* __restrict__ orow = out + (size_t)elem * TT;

    float c2 = 0.0f, h2 = 0.0f;

    float zc[16];
#pragma unroll
    for (int k = 0; k < 16; ++k) zc[k] = zrow[k << 2];

    for (int t0 = 0; t0 < TT; t0 += 16) {
        float zn[16];
        if (t0 + 16 < TT) {
#pragma unroll
            for (int k = 0; k < 16; ++k) zn[k] = zrow[((t0 + 16 + k) << 2)];
        }
        float st0 = 0.f, st1 = 0.f, st2 = 0.f, st3 = 0.f;
#pragma unroll
        for (int k = 0; k < 16; ++k) {
            const float arg = fmaf(w2h, h2, zc[k] + bb);
            const float ev  = __expf(arg * nlm);
            const float rv  = rcpf(1.0f + ev);
            const float v   = fmaf(k2, rv, k3);
            const float vi = qbcast<0>(v), vj = qbcast<1>(v);
            const float vf = qbcast<2>(v), vo = qbcast<3>(v);
            c2 = fmaf(c2, vf, vi * vj);
            h2 = ftanh(c2) * vo;
            const bool mine = (g == (k & 3));
            if ((k >> 2) == 0) st0 = mine ? h2 : st0;
            else if ((k >> 2) == 1) st1 = mine ? h2 : st1;
            else if ((k >> 2) == 2) st2 = mine ? h2 : st2;
            else st3 = mine ? h2 : st3;
        }
        orow[t0 + g]      = st0;
        orow[t0 + 4 + g]  = st1;
        orow[t0 + 8 + g]  = st2;
        orow[t0 + 12 + g] = st3;
#pragma unroll
        for (int k = 0; k < 16; ++k) zc[k] = zn[k];
    }
}

// ===================== Fallback: R11 monolithic (proven) ==================
__global__ __launch_bounds__(512)
__attribute__((amdgpu_waves_per_eu(4, 4)))
void lstm2_mono(const float* __restrict__ x,
                const float* __restrict__ W1,
                const float* __restrict__ b1,
                const float* __restrict__ W2,
                const float* __restrict__ b2,
                float* __restrict__ out)
{
    __shared__ __align__(16) float xall[TT + 4];
    __shared__ __align__(16) float h1x[2][80];
    __shared__ __align__(16) float zpq[4][4];
    __shared__ __align__(16) float h2buf[2][64];

    const int tid  = threadIdx.x;
    const int wave = tid >> 6;
    const int lane = tid & 63;
    const int b    = blockIdx.x;

    for (int i = tid; i < TT; i += 512) xall[i] = x[b * TT + i];
    if (tid < 4) xall[TT + tid] = 0.0f;

    const int u    = lane >> 3;
    const int h    = (lane >> 2) & 1;
    const int g    = lane & 3;
    const int unit = (wave << 3) + u;
    const int col  = (g << 6) + unit;

#define DECLW(k) const v2f wp##k = mk2(W1[(1 + 32*h + 2*(k)) * 256 + col], \
                                       W1[(2 + 32*h + 2*(k)) * 256 + col]);
    DECLW(0)  DECLW(1)  DECLW(2)  DECLW(3)
    DECLW(4)  DECLW(5)  DECLW(6)  DECLW(7)
    DECLW(8)  DECLW(9)  DECLW(10) DECLW(11)
    DECLW(12) DECLW(13) DECLW(14) DECLW(15)
#undef DECLW

    const float w0x   = (h == 0) ? W1[col] : 0.0f;
    const float biasF = (h == 0) ? (b1[col] + ((g == 2) ? 1.0f : 0.0f)) : 0.0f;
    const float nlm   = (g == 1) ? -2.0f : -1.0f;
    const bool  isj   = (g == 1);

    const float w2g  = W2[lane * 4 + (wave & 3)];
    const float w2h0 = W2[256], w2h1 = W2[257], w2h2 = W2[258], w2h3 = W2[259];
    const float b20 = b2[0], b21 = b2[1], b22 = b2[2], b23 = b2[3];

    float c1 = 0.0f;
    float c2 = 0.0f, h2v = 0.0f;

    const int hbase = h * 48;
    const int ridx  = lane + ((lane >> 5) << 4);
    const int widx  = (unit < 32) ? unit : unit + 16;

    if (tid < 160) ((float*)h1x)[tid] = 0.0f;
    __syncthreads();

    float* __restrict__ outb = out + b * TT;

#define STEP(P, t, xv)                                                        \
    {                                                                         \
        if ((t) < TT) {                                                       \
            const float4* hp = (const float4*)&h1x[P][hbase];                 \
            const float4 q0 = hp[0], q1 = hp[1], q2 = hp[2], q3 = hp[3];      \
            const float4 q4 = hp[4], q5 = hp[5], q6 = hp[6], q7 = hp[7];      \
            v2f a0 = mk2(fmaf((xv), w0x, biasF), 0.0f);                       \
            v2f a1 = mk2(0.f, 0.f), a2 = mk2(0.f, 0.f), a3 = mk2(0.f, 0.f);  \
            a0 = __builtin_elementwise_fma(mk2(q0.x, q0.y), wp0,  a0);        \
            a1 = __builtin_elementwise_fma(mk2(q0.z, q0.w), wp1,  a1);        \
            a2 = __builtin_elementwise_fma(mk2(q1.x, q1.y), wp2,  a2);        \
            a3 = __builtin_elementwise_fma(mk2(q1.z, q1.w), wp3,  a3);        \
            a0 = __builtin_elementwise_fma(mk2(q2.x, q2.y), wp4,  a0);        \
            a1 = __builtin_elementwise_fma(mk2(q2.z, q2.w), wp5,  a1);        \
            a2 = __builtin_elementwise_fma(mk2(q3.x, q3.y), wp6,  a2);        \
            a3 = __builtin_elementwise_fma(mk2(q3.z, q3.w), wp7,  a3);        \
            a0 = __builtin_elementwise_fma(mk2(q4.x, q4.y), wp8,  a0);        \
            a1 = __builtin_elementwise_fma(mk2(q4.z, q4.w), wp9,  a1);        \
            a2 = __builtin_elementwise_fma(mk2(q5.x, q5.y), wp10, a2);        \
            a3 = __builtin_elementwise_fma(mk2(q5.z, q5.w), wp11, a3);        \
            a0 = __builtin_elementwise_fma(mk2(q6.x, q6.y), wp12, a0);        \
            a1 = __builtin_elementwise_fma(mk2(q6.z, q6.w), wp13, a1);        \
            a2 = __builtin_elementwise_fma(mk2(q7.x, q7.y), wp14, a2);        \
            a3 = __builtin_elementwise_fma(mk2(q7.z, q7.w), wp15, a3);        \
            const v2f sv = (a0 + a1) + (a2 + a3);                             \
            const float zh = sv.x + sv.y;                                     \
            const float tshr = dppmov<0x114>(zh);                             \
            const float tshl = dppmov<0x104>(zh);                             \
            const float zfull = zh + (h ? tshr : tshl);                       \
            const float e = __expf(zfull * nlm);                              \
            const float r = rcpf(1.0f + e);                                   \
            const float v = isj ? fmaf(2.0f, r, -1.0f) : r;                   \
            const float gi = qbcast<0>(v), gj = qbcast<1>(v);                 \
            const float gf = qbcast<2>(v), go = qbcast<3>(v);                 \
            c1 = fmaf(c1, gf, gi * gj);                                       \
            const float h1v = ftanh(c1) * go;                                 \
            if ((lane & 7) == 0) h1x[(P) ^ 1][widx] = h1v;                    \
        }                                                                     \
        if (wave < 4 && (t) >= 1 && (t) <= TT) {                              \
            const float s = wave_sum63(h1x[P][ridx] * w2g);                   \
            if (lane == 63) zpq[((t) - 1) & 3][wave] = s;                     \
        }                                                                     \
        if (wave == 7 && lane == 0 && (t) >= 2 && (t) <= TT + 1) {            \
            const int st = (t) - 2;                                           \
            const float4 z4 = *(const float4*)zpq[st & 3];                    \
            const float zi = z4.x + fmaf(h2v, w2h0, b20);                     \
            const float zj = z4.y + fmaf(h2v, w2h1, b21);                     \
            const float zf = z4.z + fmaf(h2v, w2h2, b22);                     \
            const float zo = z4.w + fmaf(h2v, w2h3, b23);                     \
            c2 = c2 * fsig(zf + 1.0f) + fsig(zi) * ftanh(zj);                 \
            h2v = ftanh(c2) * fsig(zo);                                       \
            h2buf[(st >> 6) & 1][st & 63] = h2v;                              \
        }                                                                     \
        __syncthreads();                                                      \
        if (wave == 4 && (t) >= 66 && ((t) & 63) == 2) {                      \
            const int blk = ((t) - 66) >> 6;                                  \
            outb[(blk << 6) + lane] = h2buf[blk & 1][lane];                   \
        }                                                                     \
    }

    for (int it = 0; it <= TT + 2; it += 2) {
        const float2 x2 = *(const float2*)&xall[it];
        STEP(0, it,     x2.x)
        STEP(1, it + 1, x2.y)
    }
#undef STEP
}

extern "C" void kernel_launch(void* const* d_in, const int* in_sizes, int n_in,
                              void* d_out, int out_size, void* d_ws, size_t ws_size,
                              hipStream_t stream)
{
    const float* x  = (const float*)d_in[0];
    const float* W1 = (const float*)d_in[1];
    const float* b1 = (const float*)d_in[2];
    const float* W2 = (const float*)d_in[3];
    const float* b2 = (const float*)d_in[4];
    float* out = (float*)d_out;

    const size_t need = (size_t)512 * TT * 4 * sizeof(float);   // 16.8 MB
    if (ws_size >= need) {
        float* zp = (float*)d_ws;
        lstm1_kernel<<<NB, 512, 0, stream>>>(x, W1, b1, W2, zp);
        lstm2_chain<<<512 / 16, 64, 0, stream>>>(zp, W2, b2, out);
    } else {
        lstm2_mono<<<512, 512, 0, stream>>>(x, W1, b1, W2, b2, out);
    }
}

// Round 16
// 1347.263 us; speedup vs baseline: 1.4921x; 1.2109x over previous
//
#include <hip/hip_runtime.h>

#define TT 2048
#define NB 256   // 2 batch elements per block

typedef float v2f __attribute__((ext_vector_type(2)));

__device__ __forceinline__ v2f mk2(float a, float b) { v2f r; r.x = a; r.y = b; return r; }
__device__ __forceinline__ float rcpf(float x) { return __builtin_amdgcn_rcpf(x); }
__device__ __forceinline__ float fsig(float x) { return rcpf(1.0f + __expf(-x)); }
__device__ __forceinline__ float ftanh(float x) {
    return fmaf(2.0f, rcpf(1.0f + __expf(-2.0f * x)), -1.0f);
}

template<int C>
__device__ __forceinline__ float dppmov(float s) {
    return __int_as_float(__builtin_amdgcn_update_dpp(
        __float_as_int(s), __float_as_int(s), C, 0xF, 0xF, false));
}
// Full wave64 sum, result in lane 63 (verified R6-R15).
__device__ __forceinline__ float wave_sum63(float s) {
    s += dppmov<0x111>(s); s += dppmov<0x112>(s); s += dppmov<0x114>(s);
    s += dppmov<0x118>(s); s += dppmov<0x142>(s); s += dppmov<0x143>(s);
    return s;
}
template<int Q>
__device__ __forceinline__ float qbcast(float x) {
    return __int_as_float(__builtin_amdgcn_update_dpp(
        __float_as_int(x), __float_as_int(x), Q * 0x55, 0xF, 0xF, false));
}

// ========== Kernel 1: layer 1 + zp partials, 2 ELEMS PER BLOCK ==========
// 256 blocks x 8 waves (512 thr) -> 1 block/CU, 8 waves/CU, 2 w/SIMD.
// Waves 0-3 = elem A, waves 4-7 = elem B; each group is the R6-proven
// quad-gate full-K core: lane = 4u'+g, unit = (wave&3)*16+u'.
// R15 POST-MORTEM FIXES: (1) wpe(4,4)->wpe(2,2): actual occupancy is
// 2 waves/SIMD anyway; wpe(2,2) is the proven no-remat config (R4/R6
// VGPR=88) — R15's wpe(4,4) remat'd the weights (VGPR=56). (2) 64 scalar
// weights -> 32 packed v2f + pk-FMA (R13-proven resident): halves FMA
// issue and shortens the acc chain to 4 x 8-deep. Shared barrier + two
// independent elem chains co-issue (R15 measured 917 cyc/elem-step even
// WITH remat, vs R13's 803 at double the waves). Layer-2 zp rings per
// elem, flushed to global every 16 steps by a rotating wave.
__global__ __launch_bounds__(512)
__attribute__((amdgpu_waves_per_eu(2, 2)))
void lstm1_kernel(const float* __restrict__ x,
                  const float* __restrict__ W1,
                  const float* __restrict__ b1,
                  const float* __restrict__ W2,
                  float* __restrict__ zout)
{
    __shared__ __align__(16) float xall[2][TT + 4];  // per-elem input rows
    __shared__ __align__(16) float h1r[2][2][64];    // [elem][parity][unit]
    __shared__ __align__(16) float zpr[2][32][4];    // [elem][ring][gate]

    const int tid  = threadIdx.x;
    const int wave = tid >> 6;
    const int lane = tid & 63;
    const int b    = blockIdx.x;

    for (int i = tid; i < TT; i += 512) {
        xall[0][i] = x[(2 * b) * TT + i];
        xall[1][i] = x[(2 * b + 1) * TT + i];
    }
    if (tid < 8) xall[tid & 1][TT + (tid >> 1)] = 0.0f;

    const int eid  = wave >> 2;          // 0 = elem A, 1 = elem B
    const int wq   = wave & 3;           // wave-in-group
    const int g    = lane & 3;           // gate i,j,f,o
    const int u    = lane >> 2;          // local unit 0..15
    const int unit = (wq << 4) + u;      // global unit 0..63
    const int col  = (g << 6) + unit;    // W1 (65,256) column

    // 32 packed v2f weights = rows 1..64 (h-part) of this column, paired.
#define DECLW(k) const v2f wp##k = mk2(W1[(2*(k)+1)*256 + col], \
                                       W1[(2*(k)+2)*256 + col]);
    DECLW(0)  DECLW(1)  DECLW(2)  DECLW(3)
    DECLW(4)  DECLW(5)  DECLW(6)  DECLW(7)
    DECLW(8)  DECLW(9)  DECLW(10) DECLW(11)
    DECLW(12) DECLW(13) DECLW(14) DECLW(15)
    DECLW(16) DECLW(17) DECLW(18) DECLW(19)
    DECLW(20) DECLW(21) DECLW(22) DECLW(23)
    DECLW(24) DECLW(25) DECLW(26) DECLW(27)
    DECLW(28) DECLW(29) DECLW(30) DECLW(31)
#undef DECLW

    const float w0x   = W1[col];                              // x-part row 0
    const float biasF = b1[col] + ((g == 2) ? 1.0f : 0.0f);   // fold f-bias
    const float nlm   = (g == 1) ? -2.0f : -1.0f;
    const bool  isj   = (g == 1);

    const float w2g = W2[lane * 4 + wq];     // layer-2 h-part, gate = wq

    float c1 = 0.0f;                         // redundant per quad

    if (tid < 64) { h1r[0][0][tid] = 0.0f; h1r[1][0][tid] = 0.0f; }
    __syncthreads();

    float* __restrict__ zb = zout + (size_t)(2 * b + eid) * TT * 4;
    const float* __restrict__ xrow = xall[eid];

    // even m -> accs a0/a1, odd m -> a2/a3 (4 chains, 8 deep each)
#define PK(m, A, B)                                                           \
    {                                                                         \
        const float4 q = hp[m];                                               \
        A = __builtin_elementwise_fma(mk2(q.x, q.y), wp##m##_LO, A);          \
        B = __builtin_elementwise_fma(mk2(q.z, q.w), wp##m##_HI, B);          \
    }
    // helper aliases for pair indices 2m / 2m+1
#define wp0_LO  wp0
#define wp0_HI  wp1
#define wp1_LO  wp2
#define wp1_HI  wp3
#define wp2_LO  wp4
#define wp2_HI  wp5
#define wp3_LO  wp6
#define wp3_HI  wp7
#define wp4_LO  wp8
#define wp4_HI  wp9
#define wp5_LO  wp10
#define wp5_HI  wp11
#define wp6_LO  wp12
#define wp6_HI  wp13
#define wp7_LO  wp14
#define wp7_HI  wp15
#define wp8_LO  wp16
#define wp8_HI  wp17
#define wp9_LO  wp18
#define wp9_HI  wp19
#define wp10_LO wp20
#define wp10_HI wp21
#define wp11_LO wp22
#define wp11_HI wp23
#define wp12_LO wp24
#define wp12_HI wp25
#define wp13_LO wp26
#define wp13_HI wp27
#define wp14_LO wp28
#define wp14_HI wp29
#define wp15_LO wp30
#define wp15_HI wp31

#define STEP(P, t, xv)                                                        \
    {                                                                         \
        if ((t) < TT) {                                                       \
            const float4* hp = (const float4*)h1r[eid][P];                    \
            v2f a0 = mk2(fmaf((xv), w0x, biasF), 0.0f);                       \
            v2f a1 = mk2(0.f, 0.f), a2 = mk2(0.f, 0.f), a3 = mk2(0.f, 0.f);  \
            PK(0,  a0, a1) PK(1,  a2, a3) PK(2,  a0, a1) PK(3,  a2, a3)       \
            PK(4,  a0, a1) PK(5,  a2, a3) PK(6,  a0, a1) PK(7,  a2, a3)       \
            PK(8,  a0, a1) PK(9,  a2, a3) PK(10, a0, a1) PK(11, a2, a3)       \
            PK(12, a0, a1) PK(13, a2, a3) PK(14, a0, a1) PK(15, a2, a3)       \
            const v2f sv = (a0 + a1) + (a2 + a3);                             \
            const float acc = sv.x + sv.y;                                    \
            const float e = __expf(acc * nlm);                                \
            const float r = rcpf(1.0f + e);                                   \
            const float v = isj ? fmaf(2.0f, r, -1.0f) : r;                   \
            const float gi = qbcast<0>(v), gj = qbcast<1>(v);                 \
            const float gf = qbcast<2>(v), go = qbcast<3>(v);                 \
            c1 = fmaf(c1, gf, gi * gj);                                       \
            const float h1v = ftanh(c1) * go;                                 \
            if (g == 0) h1r[eid][(P) ^ 1][unit] = h1v;                        \
        }                                                                     \
        if ((t) >= 1 && (t) <= TT) {   /* layer-2 partial for step t-1 */     \
            const float s = wave_sum63(h1r[eid][P][lane] * w2g);              \
            if (lane == 63) zpr[eid][((t) - 1) & 31][wq] = s;                 \
        }                                                                     \
        __syncthreads();               /* the ONLY barrier per step */        \
        if ((t) >= 16 && (t) <= TT && ((t) & 15) == 0 &&                      \
            wq == (((t) >> 4) & 3)) {                                         \
            const int base = (t) - 16;                                        \
            const float zv = ((const float*)zpr[eid])[((base&31)<<2) + lane]; \
            zb[(size_t)(base << 2) + lane] = zv;                              \
        }                                                                     \
    }

    for (int it = 0; it <= TT; it += 2) {
        const float2 x2 = *(const float2*)&xrow[it];
        STEP(0, it,     x2.x)
        STEP(1, it + 1, x2.y)
    }
#undef STEP
#undef PK
}

// ===================== Kernel 2: layer-2 recurrence (R13, proven) ==========
__global__ __launch_bounds__(64)
void lstm2_chain(const float* __restrict__ zp,
                 const float* __restrict__ W2,
                 const float* __restrict__ b2,
                 float* __restrict__ out)
{
    const int lane = threadIdx.x & 63;
    const int e    = lane >> 2;
    const int g    = lane & 3;
    const int elem = (blockIdx.x << 4) + e;

    const float w2h = W2[256 + g];
    const float bb  = b2[g] + ((g == 2) ? 1.0f : 0.0f);
    const float nlm = (g == 1) ? -2.0f : -1.0f;
    const float k2  = (g == 1) ?  2.0f :  1.0f;
    const float k3  = (g == 1) ? -1.0f :  0.0f;

    const float* __restrict__ zrow = zp + (size_t)elem * TT * 4 + g;
    float* __restrict__ orow = out + (size_t)elem * TT;

    float c2 = 0.0f, h2 = 0.0f;

    float zc[16];
#pragma unroll
    for (int k = 0; k < 16; ++k) zc[k] = zrow[k << 2];

    for (int t0 = 0; t0 < TT; t0 += 16) {
        float zn[16];
        if (t0 + 16 < TT) {
#pragma unroll
            for (int k = 0; k < 16; ++k) zn[k] = zrow[((t0 + 16 + k) << 2)];
        }
        float st0 = 0.f, st1 = 0.f, st2 = 0.f, st3 = 0.f;
#pragma unroll
        for (int k = 0; k < 16; ++k) {
            const float arg = fmaf(w2h, h2, zc[k] + bb);
            const float ev  = __expf(arg * nlm);
            const float rv  = rcpf(1.0f + ev);
            const float v   = fmaf(k2, rv, k3);
            const float vi = qbcast<0>(v), vj = qbcast<1>(v);
            const float vf = qbcast<2>(v), vo = qbcast<3>(v);
            c2 = fmaf(c2, vf, vi * vj);
            h2 = ftanh(c2) * vo;
            const bool mine = (g == (k & 3));
            if ((k >> 2) == 0) st0 = mine ? h2 : st0;
            else if ((k >> 2) == 1) st1 = mine ? h2 : st1;
            else if ((k >> 2) == 2) st2 = mine ? h2 : st2;
            else st3 = mine ? h2 : st3;
        }
        orow[t0 + g]      = st0;
        orow[t0 + 4 + g]  = st1;
        orow[t0 + 8 + g]  = st2;
        orow[t0 + 12 + g] = st3;
#pragma unroll
        for (int k = 0; k < 16; ++k) zc[k] = zn[k];
    }
}

// ===================== Fallback: R11 monolithic (proven) ==================
__global__ __launch_bounds__(512)
__attribute__((amdgpu_waves_per_eu(4, 4)))
void lstm2_mono(const float* __restrict__ x,
                const float* __restrict__ W1,
                const float* __restrict__ b1,
                const float* __restrict__ W2,
                const float* __restrict__ b2,
                float* __restrict__ out)
{
    __shared__ __align__(16) float xall[TT + 4];
    __shared__ __align__(16) float h1x[2][80];
    __shared__ __align__(16) float zpq[4][4];
    __shared__ __align__(16) float h2buf[2][64];

    const int tid  = threadIdx.x;
    const int wave = tid >> 6;
    const int lane = tid & 63;
    const int b    = blockIdx.x;

    for (int i = tid; i < TT; i += 512) xall[i] = x[b * TT + i];
    if (tid < 4) xall[TT + tid] = 0.0f;

    const int u    = lane >> 3;
    const int h    = (lane >> 2) & 1;
    const int g    = lane & 3;
    const int unit = (wave << 3) + u;
    const int col  = (g << 6) + unit;

#define DECLW(k) const v2f wq##k = mk2(W1[(1 + 32*h + 2*(k)) * 256 + col], \
                                       W1[(2 + 32*h + 2*(k)) * 256 + col]);
    DECLW(0)  DECLW(1)  DECLW(2)  DECLW(3)
    DECLW(4)  DECLW(5)  DECLW(6)  DECLW(7)
    DECLW(8)  DECLW(9)  DECLW(10) DECLW(11)
    DECLW(12) DECLW(13) DECLW(14) DECLW(15)
#undef DECLW

    const float w0x   = (h == 0) ? W1[col] : 0.0f;
    const float biasF = (h == 0) ? (b1[col] + ((g == 2) ? 1.0f : 0.0f)) : 0.0f;
    const float nlm   = (g == 1) ? -2.0f : -1.0f;
    const bool  isj   = (g == 1);

    const float w2g  = W2[lane * 4 + (wave & 3)];
    const float w2h0 = W2[256], w2h1 = W2[257], w2h2 = W2[258], w2h3 = W2[259];
    const float b20 = b2[0], b21 = b2[1], b22 = b2[2], b23 = b2[3];

    float c1 = 0.0f;
    float c2 = 0.0f, h2v = 0.0f;

    const int hbase = h * 48;
    const int ridx  = lane + ((lane >> 5) << 4);
    const int widx  = (unit < 32) ? unit : unit + 16;

    if (tid < 160) ((float*)h1x)[tid] = 0.0f;
    __syncthreads();

    float* __restrict__ outb = out + b * TT;

#define STEP(P, t, xv)                                                        \
    {                                                                         \
        if ((t) < TT) {                                                       \
            const float4* hp = (const float4*)&h1x[P][hbase];                 \
            const float4 q0 = hp[0], q1 = hp[1], q2 = hp[2], q3 = hp[3];      \
            const float4 q4 = hp[4], q5 = hp[5], q6 = hp[6], q7 = hp[7];      \
            v2f a0 = mk2(fmaf((xv), w0x, biasF), 0.0f);                       \
            v2f a1 = mk2(0.f, 0.f), a2 = mk2(0.f, 0.f), a3 = mk2(0.f, 0.f);  \
            a0 = __builtin_elementwise_fma(mk2(q0.x, q0.y), wq0,  a0);        \
            a1 = __builtin_elementwise_fma(mk2(q0.z, q0.w), wq1,  a1);        \
            a2 = __builtin_elementwise_fma(mk2(q1.x, q1.y), wq2,  a2);        \
            a3 = __builtin_elementwise_fma(mk2(q1.z, q1.w), wq3,  a3);        \
            a0 = __builtin_elementwise_fma(mk2(q2.x, q2.y), wq4,  a0);        \
            a1 = __builtin_elementwise_fma(mk2(q2.z, q2.w), wq5,  a1);        \
            a2 = __builtin_elementwise_fma(mk2(q3.x, q3.y), wq6,  a2);        \
            a3 = __builtin_elementwise_fma(mk2(q3.z, q3.w), wq7,  a3);        \
            a0 = __builtin_elementwise_fma(mk2(q4.x, q4.y), wq8,  a0);        \
            a1 = __builtin_elementwise_fma(mk2(q4.z, q4.w), wq9,  a1);        \
            a2 = __builtin_elementwise_fma(mk2(q5.x, q5.y), wq10, a2);        \
            a3 = __builtin_elementwise_fma(mk2(q5.z, q5.w), wq11, a3);        \
            a0 = __builtin_elementwise_fma(mk2(q6.x, q6.y), wq12, a0);        \
            a1 = __builtin_elementwise_fma(mk2(q6.z, q6.w), wq13, a1);        \
            a2 = __builtin_elementwise_fma(mk2(q7.x, q7.y), wq14, a2);        \
            a3 = __builtin_elementwise_fma(mk2(q7.z, q7.w), wq15, a3);        \
            const v2f sv = (a0 + a1) + (a2 + a3);                             \
            const float zh = sv.x + sv.y;                                     \
            const float tshr = dppmov<0x114>(zh);                             \
            const float tshl = dppmov<0x104>(zh);                             \
            const float zfull = zh + (h ? tshr : tshl);                       \
            const float e = __expf(zfull * nlm);                              \
            const float r = rcpf(1.0f + e);                                   \
            const float v = isj ? fmaf(2.0f, r, -1.0f) : r;                   \
            const float gi = qbcast<0>(v), gj = qbcast<1>(v);                 \
            const float gf = qbcast<2>(v), go = qbcast<3>(v);                 \
            c1 = fmaf(c1, gf, gi * gj);                                       \
            const float h1v = ftanh(c1) * go;                                 \
            if ((lane & 7) == 0) h1x[(P) ^ 1][widx] = h1v;                    \
        }                                                                     \
        if (wave < 4 && (t) >= 1 && (t) <= TT) {                              \
            const float s = wave_sum63(h1x[P][ridx] * w2g);                   \
            if (lane == 63) zpq[((t) - 1) & 3][wave] = s;                     \
        }                                                                     \
        if (wave == 7 && lane == 0 && (t) >= 2 && (t) <= TT + 1) {            \
            const int st = (t) - 2;                                           \
            const float4 z4 = *(const float4*)zpq[st & 3];                    \
            const float zi = z4.x + fmaf(h2v, w2h0, b20);                     \
            const float zj = z4.y + fmaf(h2v, w2h1, b21);                     \
            const float zf = z4.z + fmaf(h2v, w2h2, b22);                     \
            const float zo = z4.w + fmaf(h2v, w2h3, b23);                     \
            c2 = c2 * fsig(zf + 1.0f) + fsig(zi) * ftanh(zj);                 \
            h2v = ftanh(c2) * fsig(zo);                                       \
            h2buf[(st >> 6) & 1][st & 63] = h2v;                              \
        }                                                                     \
        __syncthreads();                                                      \
        if (wave == 4 && (t) >= 66 && ((t) & 63) == 2) {                      \
            const int blk = ((t) - 66) >> 6;                                  \
            outb[(blk << 6) + lane] = h2buf[blk & 1][lane];                   \
        }                                                                     \
    }

    for (int it = 0; it <= TT + 2; it += 2) {
        const float2 x2 = *(const float2*)&xall[it];
        STEP(0, it,     x2.x)
        STEP(1, it + 1, x2.y)
    }
#undef STEP
}

extern "C" void kernel_launch(void* const* d_in, const int* in_sizes, int n_in,
                              void* d_out, int out_size, void* d_ws, size_t ws_size,
                              hipStream_t stream)
{
    const float* x  = (const float*)d_in[0];
    const float* W1 = (const float*)d_in[1];
    const float* b1 = (const float*)d_in[2];
    const float* W2 = (const float*)d_in[3];
    const float* b2 = (const float*)d_in[4];
    float* out = (float*)d_out;

    const size_t need = (size_t)512 * TT * 4 * sizeof(float);   // 16.8 MB
    if (ws_size >= need) {
        float* zp = (float*)d_ws;
        lstm1_kernel<<<NB, 512, 0, stream>>>(x, W1, b1, W2, zp);
        lstm2_chain<<<512 / 16, 64, 0, stream>>>(zp, W2, b2, out);
    } else {
        lstm2_mono<<<512, 512, 0, stream>>>(x, W1, b1, W2, b2, out);
    }
}

// Round 17
// 1230.879 us; speedup vs baseline: 1.6332x; 1.0946x over previous
//
#include <hip/hip_runtime.h>

#define TT 2048
#define NB 256   // 2 batch elements per block

typedef float v2f __attribute__((ext_vector_type(2)));

__device__ __forceinline__ v2f mk2(float a, float b) { v2f r; r.x = a; r.y = b; return r; }
__device__ __forceinline__ float rcpf(float x) { return __builtin_amdgcn_rcpf(x); }
__device__ __forceinline__ float fsig(float x) { return rcpf(1.0f + __expf(-x)); }
__device__ __forceinline__ float ftanh(float x) {
    return fmaf(2.0f, rcpf(1.0f + __expf(-2.0f * x)), -1.0f);
}

template<int C>
__device__ __forceinline__ float dppmov(float s) {
    return __int_as_float(__builtin_amdgcn_update_dpp(
        __float_as_int(s), __float_as_int(s), C, 0xF, 0xF, false));
}
template<int Q>
__device__ __forceinline__ float qbcast(float x) {
    return __int_as_float(__builtin_amdgcn_update_dpp(
        __float_as_int(x), __float_as_int(x), Q * 0x55, 0xF, 0xF, false));
}

// ===== Kernel 1: layer 1, K-SLICED COLUMN-SPANNING 2-phase step =====
// 256 blocks x 8 waves, 2 elems/block (waves 0-3 elem A, 4-7 elem B).
// R16's wall: 16 uniform ds_read_b128/wave/step (128 LDS ops/CU-step ~1536
// cyc ~ measured 1465 interval). Here wave wq reads ONLY h rows
// 16wq..16wq+15 (4 b128) and spans ALL 256 columns: lane = unit, 4 gates
// x 8 pk-FMA (32 pk, 64 weight VGPRs — same as R16). Writes 4 per-gate
// partials (conflict-free b32, gate-padded stride-72). ONE barrier. Phase B
// (lane -> (u,g) quad layout): 4 strided b32 partial reads + x/bias +
// nonlin + qbcast + c1/h1. h1 round-trip is SAME-WAVE only (no 2nd
// barrier). Layer-2 partial fully in-register: stride-4 DPP reduce ->
// bpermute gather -> DPP reduce -> 4 floats/wave to zpart ring; flusher
// sums 4 wave-partials -> R13's zout[e][t][g] format (k2 unchanged).
__global__ __launch_bounds__(512)
__attribute__((amdgpu_waves_per_eu(2, 2)))
void lstm1_kernel(const float* __restrict__ x,
                  const float* __restrict__ W1,
                  const float* __restrict__ b1,
                  const float* __restrict__ W2,
                  float* __restrict__ zout)
{
    __shared__ __align__(16) float xall[2][TT + 4];     // per-elem input
    __shared__ __align__(16) float h1row[2][64];        // [eid][unit]
    __shared__ __align__(16) float part[2][2][4][4][72];// [eid][par][w][g][u+pad]
    __shared__ __align__(16) float zpart[2][32][4][4];  // [eid][slot][w][g]

    const int tid  = threadIdx.x;
    const int wave = tid >> 6;
    const int lane = tid & 63;
    const int b    = blockIdx.x;

    for (int i = tid; i < TT; i += 512) {
        xall[0][i] = x[(2 * b) * TT + i];
        xall[1][i] = x[(2 * b + 1) * TT + i];
    }
    if (tid < 8) xall[tid & 1][TT + (tid >> 1)] = 0.0f;

    const int eid = wave >> 2;           // elem id
    const int wq  = wave & 3;            // wave-in-group = K-slice id

    // ---- Phase-A role: lane = unit (0..63); K rows 16wq..16wq+15.
    // 32 packed v2f weights: rows (16wq+2p, 16wq+2p+1), gates I,J,F,O.
#define DECLP(G, coff, p) const v2f w##G##p = \
    mk2(W1[(1 + 16*wq + 2*(p)) * 256 + (coff) + lane], \
        W1[(2 + 16*wq + 2*(p)) * 256 + (coff) + lane]);
    DECLP(I,   0, 0) DECLP(I,   0, 1) DECLP(I,   0, 2) DECLP(I,   0, 3)
    DECLP(I,   0, 4) DECLP(I,   0, 5) DECLP(I,   0, 6) DECLP(I,   0, 7)
    DECLP(J,  64, 0) DECLP(J,  64, 1) DECLP(J,  64, 2) DECLP(J,  64, 3)
    DECLP(J,  64, 4) DECLP(J,  64, 5) DECLP(J,  64, 6) DECLP(J,  64, 7)
    DECLP(F, 128, 0) DECLP(F, 128, 1) DECLP(F, 128, 2) DECLP(F, 128, 3)
    DECLP(F, 128, 4) DECLP(F, 128, 5) DECLP(F, 128, 6) DECLP(F, 128, 7)
    DECLP(O, 192, 0) DECLP(O, 192, 1) DECLP(O, 192, 2) DECLP(O, 192, 3)
    DECLP(O, 192, 4) DECLP(O, 192, 5) DECLP(O, 192, 6) DECLP(O, 192, 7)
#undef DECLP

    // ---- Phase-B role: lane -> (uB, gB) quad layout over own 16 units.
    const int gB   = lane & 3;
    const int uB   = (wq << 4) + (lane >> 2);
    const int colB = (gB << 6) + uB;
    const float w0x   = W1[colB];                            // x-part row 0
    const float biasF = b1[colB] + ((gB == 2) ? 1.0f : 0.0f);
    const float nlm   = (gB == 1) ? -2.0f : -1.0f;
    const bool  isj   = (gB == 1);
    const float w2own = W2[uB * 4 + gB];                     // layer-2 h-part
    const int   gidx  = (12 + (lane & 3) + ((lane >> 2) << 4)) & 63;

    float c1 = 0.0f;                     // quad-redundant cell state

    if (tid < 128) ((float*)h1row)[tid] = 0.0f;
    __syncthreads();

    float* __restrict__ zb = zout + (size_t)(2 * b + eid) * TT * 4;

    // hoisted LDS pointers
    float* __restrict__ pw = &part[eid][0][wq][0][lane];   // A writes (+g*72)
    const float* __restrict__ pr = &part[eid][0][0][gB][uB]; // B reads (+w*288)

#define PK4(p, hx, hy)                                                        \
    aI = __builtin_elementwise_fma(mk2(hx, hy), wI##p, aI);                   \
    aJ = __builtin_elementwise_fma(mk2(hx, hy), wJ##p, aJ);                   \
    aF = __builtin_elementwise_fma(mk2(hx, hy), wF##p, aF);                   \
    aO = __builtin_elementwise_fma(mk2(hx, hy), wO##p, aO);

#define STEP(P, t, xv)                                                        \
    {                                                                         \
        /* ---- Phase A: own K-slice of h (4 uniform b128), 32 pk-FMA */      \
        if ((t) < TT) {                                                       \
            const float4* hp = (const float4*)&h1row[eid][wq << 4];           \
            const float4 q0 = hp[0], q1 = hp[1], q2 = hp[2], q3 = hp[3];      \
            v2f aI = mk2(0.f, 0.f), aJ = mk2(0.f, 0.f);                       \
            v2f aF = mk2(0.f, 0.f), aO = mk2(0.f, 0.f);                       \
            PK4(0, q0.x, q0.y) PK4(1, q0.z, q0.w)                             \
            PK4(2, q1.x, q1.y) PK4(3, q1.z, q1.w)                             \
            PK4(4, q2.x, q2.y) PK4(5, q2.z, q2.w)                             \
            PK4(6, q3.x, q3.y) PK4(7, q3.z, q3.w)                             \
            pw[(P)*1152 + 0*72] = aI.x + aI.y;                                \
            pw[(P)*1152 + 1*72] = aJ.x + aJ.y;                                \
            pw[(P)*1152 + 2*72] = aF.x + aF.y;                                \
            pw[(P)*1152 + 3*72] = aO.x + aO.y;                                \
        }                                                                     \
        __syncthreads();   /* the ONLY barrier per step */                    \
        /* ---- flush: rotating wave sums 4 wave-partials, 16 steps/flush */  \
        if ((t) >= 16 && (t) <= TT && ((t) & 15) == 0 &&                      \
            wq == (((t) >> 4) & 3)) {                                         \
            const int base = ((t) - 16) & 31;                                 \
            const int s = lane >> 2, gg = lane & 3;                           \
            const float z0 = zpart[eid][base + s][0][gg];                     \
            const float z1 = zpart[eid][base + s][1][gg];                     \
            const float z2 = zpart[eid][base + s][2][gg];                     \
            const float z3 = zpart[eid][base + s][3][gg];                     \
            zb[(size_t)(((t) - 16) + s) * 4 + gg] = (z0 + z1) + (z2 + z3);    \
        }                                                                     \
        /* ---- Phase B: reduce partials, nonlin, recurrence */               \
        if ((t) < TT) {                                                       \
            const float p0 = pr[(P)*1152 + 0*288];                            \
            const float p1 = pr[(P)*1152 + 1*288];                            \
            const float p2 = pr[(P)*1152 + 2*288];                            \
            const float p3 = pr[(P)*1152 + 3*288];                            \
            const float acc = fmaf((xv), w0x, biasF) + ((p0 + p1)+(p2 + p3)); \
            const float e = __expf(acc * nlm);                                \
            const float r = rcpf(1.0f + e);                                   \
            const float v = isj ? fmaf(2.0f, r, -1.0f) : r;                   \
            const float gi = qbcast<0>(v), gj = qbcast<1>(v);                 \
            const float gf = qbcast<2>(v), go = qbcast<3>(v);                 \
            c1 = fmaf(c1, gf, gi * gj);                                       \
            const float h1v = ftanh(c1) * go;                                 \
            if (gB == 0) h1row[eid][uB] = h1v;   /* own slice, same wave */   \
            /* layer-2 partial in-register: stride-4 reduce -> gather */      \
            const float prod = h1v * w2own;                                   \
            float s1 = prod + dppmov<0x114>(prod);   /* row_shr:4 */          \
            s1 = s1 + dppmov<0x118>(s1);             /* row_shr:8 */          \
            const float gv = __shfl(s1, gidx, 64);   /* gather (g,row) */     \
            float s2 = gv + dppmov<0x114>(gv);                                \
            s2 = s2 + dppmov<0x118>(s2);                                      \
            if ((lane & ~3) == 12)                   /* lanes 12..15 */       \
                zpart[eid][(t) & 31][wq][lane - 12] = s2;                     \
        }                                                                     \
    }

    for (int it = 0; it <= TT; it += 2) {
        const float2 x2 = *(const float2*)&xall[eid][it];
        STEP(0, it,     x2.x)
        STEP(1, it + 1, x2.y)
    }
#undef STEP
#undef PK4
}

// ===== Kernel 2: layer-2 recurrence (R13, proven, format unchanged) =====
__global__ __launch_bounds__(64)
void lstm2_chain(const float* __restrict__ zp,
                 const float* __restrict__ W2,
                 const float* __restrict__ b2,
                 float* __restrict__ out)
{
    const int lane = threadIdx.x & 63;
    const int e    = lane >> 2;
    const int g    = lane & 3;
    const int elem = (blockIdx.x << 4) + e;

    const float w2h = W2[256 + g];
    const float bb  = b2[g] + ((g == 2) ? 1.0f : 0.0f);
    const float nlm = (g == 1) ? -2.0f : -1.0f;
    const float k2  = (g == 1) ?  2.0f :  1.0f;
    const float k3  = (g == 1) ? -1.0f :  0.0f;

    const float* __restrict__ zrow = zp + (size_t)elem * TT * 4 + g;
    float* __restrict__ orow = out + (size_t)elem * TT;

    float c2 = 0.0f, h2 = 0.0f;

    float zc[16];
#pragma unroll
    for (int k = 0; k < 16; ++k) zc[k] = zrow[k << 2];

    for (int t0 = 0; t0 < TT; t0 += 16) {
        float zn[16];
        if (t0 + 16 < TT) {
#pragma unroll
            for (int k = 0; k < 16; ++k) zn[k] = zrow[((t0 + 16 + k) << 2)];
        }
        float st0 = 0.f, st1 = 0.f, st2 = 0.f, st3 = 0.f;
#pragma unroll
        for (int k = 0; k < 16; ++k) {
            const float arg = fmaf(w2h, h2, zc[k] + bb);
            const float ev  = __expf(arg * nlm);
            const float rv  = rcpf(1.0f + ev);
            const float v   = fmaf(k2, rv, k3);
            const float vi = qbcast<0>(v), vj = qbcast<1>(v);
            const float vf = qbcast<2>(v), vo = qbcast<3>(v);
            c2 = fmaf(c2, vf, vi * vj);
            h2 = ftanh(c2) * vo;
            const bool mine = (g == (k & 3));
            if ((k >> 2) == 0) st0 = mine ? h2 : st0;
            else if ((k >> 2) == 1) st1 = mine ? h2 : st1;
            else if ((k >> 2) == 2) st2 = mine ? h2 : st2;
            else st3 = mine ? h2 : st3;
        }
        orow[t0 + g]      = st0;
        orow[t0 + 4 + g]  = st1;
        orow[t0 + 8 + g]  = st2;
        orow[t0 + 12 + g] = st3;
#pragma unroll
        for (int k = 0; k < 16; ++k) zc[k] = zn[k];
    }
}

// ===== Fallback: monolithic (R11 core, proven) =====
__global__ __launch_bounds__(512)
__attribute__((amdgpu_waves_per_eu(4, 4)))
void lstm2_mono(const float* __restrict__ x,
                const float* __restrict__ W1,
                const float* __restrict__ b1,
                const float* __restrict__ W2,
                const float* __restrict__ b2,
                float* __restrict__ out)
{
    __shared__ __align__(16) float xall[TT + 4];
    __shared__ __align__(16) float h1x[2][80];
    __shared__ __align__(16) float zpq[4][4];
    __shared__ __align__(16) float h2buf[2][64];

    const int tid  = threadIdx.x;
    const int wave = tid >> 6;
    const int lane = tid & 63;
    const int b    = blockIdx.x;

    for (int i = tid; i < TT; i += 512) xall[i] = x[b * TT + i];
    if (tid < 4) xall[TT + tid] = 0.0f;

    const int u    = lane >> 3;
    const int h    = (lane >> 2) & 1;
    const int g    = lane & 3;
    const int unit = (wave << 3) + u;
    const int col  = (g << 6) + unit;

#define DECLW(k) const v2f wq##k = mk2(W1[(1 + 32*h + 2*(k)) * 256 + col], \
                                       W1[(2 + 32*h + 2*(k)) * 256 + col]);
    DECLW(0)  DECLW(1)  DECLW(2)  DECLW(3)
    DECLW(4)  DECLW(5)  DECLW(6)  DECLW(7)
    DECLW(8)  DECLW(9)  DECLW(10) DECLW(11)
    DECLW(12) DECLW(13) DECLW(14) DECLW(15)
#undef DECLW

    const float w0x   = (h == 0) ? W1[col] : 0.0f;
    const float biasF = (h == 0) ? (b1[col] + ((g == 2) ? 1.0f : 0.0f)) : 0.0f;
    const float nlm   = (g == 1) ? -2.0f : -1.0f;
    const bool  isj   = (g == 1);

    const float w2g  = W2[lane * 4 + (wave & 3)];
    const float w2h0 = W2[256], w2h1 = W2[257], w2h2 = W2[258], w2h3 = W2[259];
    const float b20 = b2[0], b21 = b2[1], b22 = b2[2], b23 = b2[3];

    float c1 = 0.0f;
    float c2 = 0.0f, h2v = 0.0f;

    const int hbase = h * 48;
    const int ridx  = lane + ((lane >> 5) << 4);
    const int widx  = (unit < 32) ? unit : unit + 16;

    if (tid < 160) ((float*)h1x)[tid] = 0.0f;
    __syncthreads();

    float* __restrict__ outb = out + b * TT;

    // wave_sum63 inline (lane63 total)
#define WSUM(s) ({ float _s = (s);                                            \
    _s += dppmov<0x111>(_s); _s += dppmov<0x112>(_s); _s += dppmov<0x114>(_s);\
    _s += dppmov<0x118>(_s); _s += dppmov<0x142>(_s); _s += dppmov<0x143>(_s);\
    _s; })

#define STEP(P, t, xv)                                                        \
    {                                                                         \
        if ((t) < TT) {                                                       \
            const float4* hp = (const float4*)&h1x[P][hbase];                 \
            const float4 q0 = hp[0], q1 = hp[1], q2 = hp[2], q3 = hp[3];      \
            const float4 q4 = hp[4], q5 = hp[5], q6 = hp[6], q7 = hp[7];      \
            v2f a0 = mk2(fmaf((xv), w0x, biasF), 0.0f);                       \
            v2f a1 = mk2(0.f, 0.f), a2 = mk2(0.f, 0.f), a3 = mk2(0.f, 0.f);  \
            a0 = __builtin_elementwise_fma(mk2(q0.x, q0.y), wq0,  a0);        \
            a1 = __builtin_elementwise_fma(mk2(q0.z, q0.w), wq1,  a1);        \
            a2 = __builtin_elementwise_fma(mk2(q1.x, q1.y), wq2,  a2);        \
            a3 = __builtin_elementwise_fma(mk2(q1.z, q1.w), wq3,  a3);        \
            a0 = __builtin_elementwise_fma(mk2(q2.x, q2.y), wq4,  a0);        \
            a1 = __builtin_elementwise_fma(mk2(q2.z, q2.w), wq5,  a1);        \
            a2 = __builtin_elementwise_fma(mk2(q3.x, q3.y), wq6,  a2);        \
            a3 = __builtin_elementwise_fma(mk2(q3.z, q3.w), wq7,  a3);        \
            a0 = __builtin_elementwise_fma(mk2(q4.x, q4.y), wq8,  a0);        \
            a1 = __builtin_elementwise_fma(mk2(q4.z, q4.w), wq9,  a1);        \
            a2 = __builtin_elementwise_fma(mk2(q5.x, q5.y), wq10, a2);        \
            a3 = __builtin_elementwise_fma(mk2(q5.z, q5.w), wq11, a3);        \
            a0 = __builtin_elementwise_fma(mk2(q6.x, q6.y), wq12, a0);        \
            a1 = __builtin_elementwise_fma(mk2(q6.z, q6.w), wq13, a1);        \
            a2 = __builtin_elementwise_fma(mk2(q7.x, q7.y), wq14, a2);        \
            a3 = __builtin_elementwise_fma(mk2(q7.z, q7.w), wq15, a3);        \
            const v2f sv = (a0 + a1) + (a2 + a3);                             \
            const float zh = sv.x + sv.y;                                     \
            const float tshr = dppmov<0x114>(zh);                             \
            const float tshl = dppmov<0x104>(zh);                             \
            const float zfull = zh + (h ? tshr : tshl);                       \
            const float e = __expf(zfull * nlm);                              \
            const float r = rcpf(1.0f + e);                                   \
            const float v = isj ? fmaf(2.0f, r, -1.0f) : r;                   \
            const float gi = qbcast<0>(v), gj = qbcast<1>(v);                 \
            const float gf = qbcast<2>(v), go = qbcast<3>(v);                 \
            c1 = fmaf(c1, gf, gi * gj);                                       \
            const float h1v = ftanh(c1) * go;                                 \
            if ((lane & 7) == 0) h1x[(P) ^ 1][widx] = h1v;                    \
        }                                                                     \
        if (wave < 4 && (t) >= 1 && (t) <= TT) {                              \
            const float s = WSUM(h1x[P][ridx] * w2g);                         \
            if (lane == 63) zpq[((t) - 1) & 3][wave] = s;                     \
        }                                                                     \
        if (wave == 7 && lane == 0 && (t) >= 2 && (t) <= TT + 1) {            \
            const int st = (t) - 2;                                           \
            const float4 z4 = *(const float4*)zpq[st & 3];                    \
            const float zi = z4.x + fmaf(h2v, w2h0, b20);                     \
            const float zj = z4.y + fmaf(h2v, w2h1, b21);                     \
            const float zf = z4.z + fmaf(h2v, w2h2, b22);                     \
            const float zo = z4.w + fmaf(h2v, w2h3, b23);                     \
            c2 = c2 * fsig(zf + 1.0f) + fsig(zi) * ftanh(zj);                 \
            h2v = ftanh(c2) * fsig(zo);                                       \
            h2buf[(st >> 6) & 1][st & 63] = h2v;                              \
        }                                                                     \
        __syncthreads();                                                      \
        if (wave == 4 && (t) >= 66 && ((t) & 63) == 2) {                      \
            const int blk = ((t) - 66) >> 6;                                  \
            outb[(blk << 6) + lane] = h2buf[blk & 1][lane];                   \
        }                                                                     \
    }

    for (int it = 0; it <= TT + 2; it += 2) {
        const float2 x2 = *(const float2*)&xall[it];
        STEP(0, it,     x2.x)
        STEP(1, it + 1, x2.y)
    }
#undef STEP
#undef WSUM
}

extern "C" void kernel_launch(void* const* d_in, const int* in_sizes, int n_in,
                              void* d_out, int out_size, void* d_ws, size_t ws_size,
                              hipStream_t stream)
{
    const float* x  = (const float*)d_in[0];
    const float* W1 = (const float*)d_in[1];
    const float* b1 = (const float*)d_in[2];
    const float* W2 = (const float*)d_in[3];
    const float* b2 = (const float*)d_in[4];
    float* out = (float*)d_out;

    const size_t need = (size_t)512 * TT * 4 * sizeof(float);   // 16.8 MB
    if (ws_size >= need) {
        float* zp = (float*)d_ws;
        lstm1_kernel<<<NB, 512, 0, stream>>>(x, W1, b1, W2, zp);
        lstm2_chain<<<512 / 16, 64, 0, stream>>>(zp, W2, b2, out);
    } else {
        lstm2_mono<<<512, 512, 0, stream>>>(x, W1, b1, W2, b2, out);
    }
}

// Round 19
// 1039.025 us; speedup vs baseline: 1.9348x; 1.1846x over previous
//
#include <hip/hip_runtime.h>

#define TT 2048

typedef float v2f __attribute__((ext_vector_type(2)));
typedef _Float16 h2v __attribute__((ext_vector_type(2)));

__device__ __forceinline__ v2f mk2(float a, float b) { v2f r; r.x = a; r.y = b; return r; }
__device__ __forceinline__ float rcpf(float x) { return __builtin_amdgcn_rcpf(x); }
__device__ __forceinline__ float fsig(float x) { return rcpf(1.0f + __expf(-x)); }
__device__ __forceinline__ float ftanh(float x) {
    return fmaf(2.0f, rcpf(1.0f + __expf(-2.0f * x)), -1.0f);
}

template<int C>
__device__ __forceinline__ float dppmov(float s) {
    return __int_as_float(__builtin_amdgcn_update_dpp(
        __float_as_int(s), __float_as_int(s), C, 0xF, 0xF, false));
}
template<int Q>
__device__ __forceinline__ float qbcast(float x) {
    return __int_as_float(__builtin_amdgcn_update_dpp(
        __float_as_int(x), __float_as_int(x), Q * 0x55, 0xF, 0xF, false));
}

#if __has_builtin(__builtin_amdgcn_fdot2)
#define DOT2(a, b, c) __builtin_amdgcn_fdot2((a), (b), (c), false)
#else
#define DOT2(a, b, c) fmaf((float)(a).x, (float)(b).x, \
                      fmaf((float)(a).y, (float)(b).y, (c)))
#endif

__device__ __forceinline__ h2v pk2(float a, float b) {
#if __has_builtin(__builtin_amdgcn_cvt_pkrtz)
    return __builtin_bit_cast(h2v, __builtin_amdgcn_cvt_pkrtz(a, b));  // R18 fix
#else
    h2v r; r.x = (_Float16)a; r.y = (_Float16)b; return r;
#endif
}
__device__ __forceinline__ h2v bch(int v) { return __builtin_bit_cast(h2v, v); }

// ===== Kernel 1: ONE WAVE PER ELEMENT — zero barriers, zero cross-wave =====
// 512 blocks x 64 threads. Lane = unit u; each lane computes ALL 4 gates of
// its unit: weights as 128 packed-f16 half2 VGPRs (v_dot2_f32_f16: products
// exact in f32, f32 accumulate — only input-quantization error). h1 crosses
// steps through a 16-slot f16 LDS ring: 1 ds_write_b16 + 8 uniform
// ds_read_b128 per step, SAME-WAVE ordering via lgkmcnt — no __syncthreads.
// This removes R17's structural floor (partial-exchange round trip + barrier
// + ~120 LDS ops/CU-step). Layer-2 partials batched every 16 steps: lane
// (t,g) reads its h-row as 8 b128 (2-way bank alias = free, m136) and
// 32-dot2s against register f16 W2 -> coalesced store in R13's zout format.
__global__ __launch_bounds__(64)
__attribute__((amdgpu_waves_per_eu(2, 2)))
void lstm1_f16(const float* __restrict__ x,
               const float* __restrict__ W1,
               const float* __restrict__ b1,
               const float* __restrict__ W2,
               float* __restrict__ zout)
{
    __shared__ __align__(16) float xall[TT];
    __shared__ __align__(16) _Float16 hring[16 * 72];  // 144B/slot

    const int lane = threadIdx.x & 63;
    const int e    = blockIdx.x;
    const int u    = lane;

    for (int i = lane; i < TT; i += 64) xall[i] = x[(size_t)e * TT + i];
    for (int i = lane; i < 576; i += 64) ((int*)hring)[i] = 0;

    // Layer-1 weights: gate G column = G*64+u; h rows 1..64 as 32 half2/gate.
#define DWQ(G, GO, q) \
    const h2v w##G##q##x = pk2(W1[(1+8*(q))*256 + (GO)*64 + u], W1[(2+8*(q))*256 + (GO)*64 + u]); \
    const h2v w##G##q##y = pk2(W1[(3+8*(q))*256 + (GO)*64 + u], W1[(4+8*(q))*256 + (GO)*64 + u]); \
    const h2v w##G##q##z = pk2(W1[(5+8*(q))*256 + (GO)*64 + u], W1[(6+8*(q))*256 + (GO)*64 + u]); \
    const h2v w##G##q##w = pk2(W1[(7+8*(q))*256 + (GO)*64 + u], W1[(8+8*(q))*256 + (GO)*64 + u]);
    DWQ(I, 0, 0) DWQ(I, 0, 1) DWQ(I, 0, 2) DWQ(I, 0, 3)
    DWQ(I, 0, 4) DWQ(I, 0, 5) DWQ(I, 0, 6) DWQ(I, 0, 7)
    DWQ(J, 1, 0) DWQ(J, 1, 1) DWQ(J, 1, 2) DWQ(J, 1, 3)
    DWQ(J, 1, 4) DWQ(J, 1, 5) DWQ(J, 1, 6) DWQ(J, 1, 7)
    DWQ(F, 2, 0) DWQ(F, 2, 1) DWQ(F, 2, 2) DWQ(F, 2, 3)
    DWQ(F, 2, 4) DWQ(F, 2, 5) DWQ(F, 2, 6) DWQ(F, 2, 7)
    DWQ(O, 3, 0) DWQ(O, 3, 1) DWQ(O, 3, 2) DWQ(O, 3, 3)
    DWQ(O, 3, 4) DWQ(O, 3, 5) DWQ(O, 3, 6) DWQ(O, 3, 7)
#undef DWQ

    const float w0I = W1[u],        bI = b1[u];
    const float w0J = W1[64 + u],   bJ = b1[64 + u];
    const float w0F = W1[128 + u],  bF = b1[128 + u] + 1.0f;  // forget bias
    const float w0O = W1[192 + u],  bO = b1[192 + u];

    // Layer-2 batch role: lane = tl*4 + g; W2 h-part column g as 32 half2.
    const int tl = lane >> 2, gq = lane & 3;
#define DW2(q) \
    const h2v w2##q##x = pk2(W2[(8*(q)+0)*4 + gq], W2[(8*(q)+1)*4 + gq]); \
    const h2v w2##q##y = pk2(W2[(8*(q)+2)*4 + gq], W2[(8*(q)+3)*4 + gq]); \
    const h2v w2##q##z = pk2(W2[(8*(q)+4)*4 + gq], W2[(8*(q)+5)*4 + gq]); \
    const h2v w2##q##w = pk2(W2[(8*(q)+6)*4 + gq], W2[(8*(q)+7)*4 + gq]);
    DW2(0) DW2(1) DW2(2) DW2(3) DW2(4) DW2(5) DW2(6) DW2(7)
#undef DW2

    float c1 = 0.0f;
    __syncthreads();   // single wave: trivially cheap, covers init stores

    float* __restrict__ zb = zout + (size_t)e * TT * 4;

#define DGQ(G, q, v) \
    acc##G = DOT2(bch((v).x), w##G##q##x, acc##G); \
    acc##G = DOT2(bch((v).y), w##G##q##y, acc##G); \
    acc##G = DOT2(bch((v).z), w##G##q##z, acc##G); \
    acc##G = DOT2(bch((v).w), w##G##q##w, acc##G);

    for (int t = 0; t < TT; ++t) {
        // h(t-1) from ring slot (t-1)&15 (slot 15 zeroed for t=0)
        const int4* hp = (const int4*)&hring[((t - 1) & 15) * 72];
        const int4 q0 = hp[0], q1 = hp[1], q2 = hp[2], q3 = hp[3];
        const int4 q4 = hp[4], q5 = hp[5], q6 = hp[6], q7 = hp[7];
        const float xt = xall[t];
        float accI = fmaf(xt, w0I, bI);
        float accJ = fmaf(xt, w0J, bJ);
        float accF = fmaf(xt, w0F, bF);
        float accO = fmaf(xt, w0O, bO);
        DGQ(I, 0, q0) DGQ(J, 0, q0) DGQ(F, 0, q0) DGQ(O, 0, q0)
        DGQ(I, 1, q1) DGQ(J, 1, q1) DGQ(F, 1, q1) DGQ(O, 1, q1)
        DGQ(I, 2, q2) DGQ(J, 2, q2) DGQ(F, 2, q2) DGQ(O, 2, q2)
        DGQ(I, 3, q3) DGQ(J, 3, q3) DGQ(F, 3, q3) DGQ(O, 3, q3)
        DGQ(I, 4, q4) DGQ(J, 4, q4) DGQ(F, 4, q4) DGQ(O, 4, q4)
        DGQ(I, 5, q5) DGQ(J, 5, q5) DGQ(F, 5, q5) DGQ(O, 5, q5)
        DGQ(I, 6, q6) DGQ(J, 6, q6) DGQ(F, 6, q6) DGQ(O, 6, q6)
        DGQ(I, 7, q7) DGQ(J, 7, q7) DGQ(F, 7, q7) DGQ(O, 7, q7)
        // nonlinearities (all f32)
        const float i_ = fsig(accI);
        const float j_ = ftanh(accJ);
        const float f_ = fsig(accF);          // +1 folded into bF
        const float o_ = fsig(accO);
        c1 = fmaf(c1, f_, i_ * j_);
        const float h1 = ftanh(c1) * o_;
        hring[(t & 15) * 72 + u] = (_Float16)h1;   // same-wave visible (lgkm)

        // layer-2 partial batch every 16 steps (slots 0..15 = steps t-15..t)
        if ((t & 15) == 15) {
            const int4* hb = (const int4*)&hring[tl * 72];
            const int4 b0 = hb[0], b1q = hb[1], b2q = hb[2], b3 = hb[3];
            const int4 b4 = hb[4], b5 = hb[5], b6 = hb[6], b7 = hb[7];
            float z2 = 0.0f;
#define BQ(q, v) \
            z2 = DOT2(bch((v).x), w2##q##x, z2); \
            z2 = DOT2(bch((v).y), w2##q##y, z2); \
            z2 = DOT2(bch((v).z), w2##q##z, z2); \
            z2 = DOT2(bch((v).w), w2##q##w, z2);
            BQ(0, b0) BQ(1, b1q) BQ(2, b2q) BQ(3, b3)
            BQ(4, b4) BQ(5, b5) BQ(6, b6) BQ(7, b7)
#undef BQ
            zb[(size_t)(t - 15 + tl) * 4 + gq] = z2;   // lane-coalesced
        }
    }
#undef DGQ
}

// ===== Kernel 2: layer-2 recurrence (R13, proven, format unchanged) =====
__global__ __launch_bounds__(64)
void lstm2_chain(const float* __restrict__ zp,
                 const float* __restrict__ W2,
                 const float* __restrict__ b2,
                 float* __restrict__ out)
{
    const int lane = threadIdx.x & 63;
    const int e    = lane >> 2;
    const int g    = lane & 3;
    const int elem = (blockIdx.x << 4) + e;

    const float w2h = W2[256 + g];
    const float bb  = b2[g] + ((g == 2) ? 1.0f : 0.0f);
    const float nlm = (g == 1) ? -2.0f : -1.0f;
    const float k2  = (g == 1) ?  2.0f :  1.0f;
    const float k3  = (g == 1) ? -1.0f :  0.0f;

    const float* __restrict__ zrow = zp + (size_t)elem * TT * 4 + g;
    float* __restrict__ orow = out + (size_t)elem * TT;

    float c2 = 0.0f, h2 = 0.0f;

    float zc[16];
#pragma unroll
    for (int k = 0; k < 16; ++k) zc[k] = zrow[k << 2];

    for (int t0 = 0; t0 < TT; t0 += 16) {
        float zn[16];
        if (t0 + 16 < TT) {
#pragma unroll
            for (int k = 0; k < 16; ++k) zn[k] = zrow[((t0 + 16 + k) << 2)];
        }
        float st0 = 0.f, st1 = 0.f, st2 = 0.f, st3 = 0.f;
#pragma unroll
        for (int k = 0; k < 16; ++k) {
            const float arg = fmaf(w2h, h2, zc[k] + bb);
            const float ev  = __expf(arg * nlm);
            const float rv  = rcpf(1.0f + ev);
            const float v   = fmaf(k2, rv, k3);
            const float vi = qbcast<0>(v), vj = qbcast<1>(v);
            const float vf = qbcast<2>(v), vo = qbcast<3>(v);
            c2 = fmaf(c2, vf, vi * vj);
            h2 = ftanh(c2) * vo;
            const bool mine = (g == (k & 3));
            if ((k >> 2) == 0) st0 = mine ? h2 : st0;
            else if ((k >> 2) == 1) st1 = mine ? h2 : st1;
            else if ((k >> 2) == 2) st2 = mine ? h2 : st2;
            else st3 = mine ? h2 : st3;
        }
        orow[t0 + g]      = st0;
        orow[t0 + 4 + g]  = st1;
        orow[t0 + 8 + g]  = st2;
        orow[t0 + 12 + g] = st3;
#pragma unroll
        for (int k = 0; k < 16; ++k) zc[k] = zn[k];
    }
}

// ===== Fallback: monolithic (R11 core, proven) =====
__global__ __launch_bounds__(512)
__attribute__((amdgpu_waves_per_eu(4, 4)))
void lstm2_mono(const float* __restrict__ x,
                const float* __restrict__ W1,
                const float* __restrict__ b1,
                const float* __restrict__ W2,
                const float* __restrict__ b2,
                float* __restrict__ out)
{
    __shared__ __align__(16) float xall[TT + 4];
    __shared__ __align__(16) float h1x[2][80];
    __shared__ __align__(16) float zpq[4][4];
    __shared__ __align__(16) float h2buf[2][64];

    const int tid  = threadIdx.x;
    const int wave = tid >> 6;
    const int lane = tid & 63;
    const int b    = blockIdx.x;

    for (int i = tid; i < TT; i += 512) xall[i] = x[b * TT + i];
    if (tid < 4) xall[TT + tid] = 0.0f;

    const int u    = lane >> 3;
    const int h    = (lane >> 2) & 1;
    const int g    = lane & 3;
    const int unit = (wave << 3) + u;
    const int col  = (g << 6) + unit;

#define DECLW(k) const v2f wq##k = mk2(W1[(1 + 32*h + 2*(k)) * 256 + col], \
                                       W1[(2 + 32*h + 2*(k)) * 256 + col]);
    DECLW(0)  DECLW(1)  DECLW(2)  DECLW(3)
    DECLW(4)  DECLW(5)  DECLW(6)  DECLW(7)
    DECLW(8)  DECLW(9)  DECLW(10) DECLW(11)
    DECLW(12) DECLW(13) DECLW(14) DECLW(15)
#undef DECLW

    const float w0x   = (h == 0) ? W1[col] : 0.0f;
    const float biasF = (h == 0) ? (b1[col] + ((g == 2) ? 1.0f : 0.0f)) : 0.0f;
    const float nlm   = (g == 1) ? -2.0f : -1.0f;
    const bool  isj   = (g == 1);

    const float w2g  = W2[lane * 4 + (wave & 3)];
    const float w2h0 = W2[256], w2h1 = W2[257], w2h2 = W2[258], w2h3 = W2[259];
    const float b20 = b2[0], b21 = b2[1], b22 = b2[2], b23 = b2[3];

    float c1 = 0.0f;
    float c2 = 0.0f, h2v2 = 0.0f;

    const int hbase = h * 48;
    const int ridx  = lane + ((lane >> 5) << 4);
    const int widx  = (unit < 32) ? unit : unit + 16;

    if (tid < 160) ((float*)h1x)[tid] = 0.0f;
    __syncthreads();

    float* __restrict__ outb = out + b * TT;

#define WSUM(s) ({ float _s = (s);                                            \
    _s += dppmov<0x111>(_s); _s += dppmov<0x112>(_s); _s += dppmov<0x114>(_s);\
    _s += dppmov<0x118>(_s); _s += dppmov<0x142>(_s); _s += dppmov<0x143>(_s);\
    _s; })

#define STEP(P, t, xv)                                                        \
    {                                                                         \
        if ((t) < TT) {                                                       \
            const float4* hp = (const float4*)&h1x[P][hbase];                 \
            const float4 q0 = hp[0], q1 = hp[1], q2 = hp[2], q3 = hp[3];      \
            const float4 q4 = hp[4], q5 = hp[5], q6 = hp[6], q7 = hp[7];      \
            v2f a0 = mk2(fmaf((xv), w0x, biasF), 0.0f);                       \
            v2f a1 = mk2(0.f, 0.f), a2 = mk2(0.f, 0.f), a3 = mk2(0.f, 0.f);  \
            a0 = __builtin_elementwise_fma(mk2(q0.x, q0.y), wq0,  a0);        \
            a1 = __builtin_elementwise_fma(mk2(q0.z, q0.w), wq1,  a1);        \
            a2 = __builtin_elementwise_fma(mk2(q1.x, q1.y), wq2,  a2);        \
            a3 = __builtin_elementwise_fma(mk2(q1.z, q1.w), wq3,  a3);        \
            a0 = __builtin_elementwise_fma(mk2(q2.x, q2.y), wq4,  a0);        \
            a1 = __builtin_elementwise_fma(mk2(q2.z, q2.w), wq5,  a1);        \
            a2 = __builtin_elementwise_fma(mk2(q3.x, q3.y), wq6,  a2);        \
            a3 = __builtin_elementwise_fma(mk2(q3.z, q3.w), wq7,  a3);        \
            a0 = __builtin_elementwise_fma(mk2(q4.x, q4.y), wq8,  a0);        \
            a1 = __builtin_elementwise_fma(mk2(q4.z, q4.w), wq9,  a1);        \
            a2 = __builtin_elementwise_fma(mk2(q5.x, q5.y), wq10, a2);        \
            a3 = __builtin_elementwise_fma(mk2(q5.z, q5.w), wq11, a3);        \
            a0 = __builtin_elementwise_fma(mk2(q6.x, q6.y), wq12, a0);        \
            a1 = __builtin_elementwise_fma(mk2(q6.z, q6.w), wq13, a1);        \
            a2 = __builtin_elementwise_fma(mk2(q7.x, q7.y), wq14, a2);        \
            a3 = __builtin_elementwise_fma(mk2(q7.z, q7.w), wq15, a3);        \
            const v2f sv = (a0 + a1) + (a2 + a3);                             \
            const float zh = sv.x + sv.y;                                     \
            const float tshr = dppmov<0x114>(zh);                             \
            const float tshl = dppmov<0x104>(zh);                             \
            const float zfull = zh + (h ? tshr : tshl);                       \
            const float e = __expf(zfull * nlm);                              \
            const float r = rcpf(1.0f + e);                                   \
            const float v = isj ? fmaf(2.0f, r, -1.0f) : r;                   \
            const float gi = qbcast<0>(v), gj = qbcast<1>(v);                 \
            const float gf = qbcast<2>(v), go = qbcast<3>(v);                 \
            c1 = fmaf(c1, gf, gi * gj);                                       \
            const float h1v = ftanh(c1) * go;                                 \
            if ((lane & 7) == 0) h1x[(P) ^ 1][widx] = h1v;                    \
        }                                                                     \
        if (wave < 4 && (t) >= 1 && (t) <= TT) {                              \
            const float s = WSUM(h1x[P][ridx] * w2g);                         \
            if (lane == 63) zpq[((t) - 1) & 3][wave] = s;                     \
        }                                                                     \
        if (wave == 7 && lane == 0 && (t) >= 2 && (t) <= TT + 1) {            \
            const int st = (t) - 2;                                           \
            const float4 z4 = *(const float4*)zpq[st & 3];                    \
            const float zi = z4.x + fmaf(h2v2, w2h0, b20);                    \
            const float zj = z4.y + fmaf(h2v2, w2h1, b21);                    \
            const float zf = z4.z + fmaf(h2v2, w2h2, b22);                    \
            const float zo = z4.w + fmaf(h2v2, w2h3, b23);                    \
            c2 = c2 * fsig(zf + 1.0f) + fsig(zi) * ftanh(zj);                 \
            h2v2 = ftanh(c2) * fsig(zo);                                      \
            h2buf[(st >> 6) & 1][st & 63] = h2v2;                             \
        }                                                                     \
        __syncthreads();                                                      \
        if (wave == 4 && (t) >= 66 && ((t) & 63) == 2) {                      \
            const int blk = ((t) - 66) >> 6;                                  \
            outb[(blk << 6) + lane] = h2buf[blk & 1][lane];                   \
        }                                                                     \
    }

    for (int it = 0; it <= TT + 2; it += 2) {
        const float2 x2 = *(const float2*)&xall[it];
        STEP(0, it,     x2.x)
        STEP(1, it + 1, x2.y)
    }
#undef STEP
#undef WSUM
}

extern "C" void kernel_launch(void* const* d_in, const int* in_sizes, int n_in,
                              void* d_out, int out_size, void* d_ws, size_t ws_size,
                              hipStream_t stream)
{
    const float* x  = (const float*)d_in[0];
    const float* W1 = (const float*)d_in[1];
    const float* b1 = (const float*)d_in[2];
    const float* W2 = (const float*)d_in[3];
    const float* b2 = (const float*)d_in[4];
    float* out = (float*)d_out;

    const size_t need = (size_t)512 * TT * 4 * sizeof(float);   // 16.8 MB
    if (ws_size >= need) {
        float* zp = (float*)d_ws;
        lstm1_f16<<<512, 64, 0, stream>>>(x, W1, b1, W2, zp);
        lstm2_chain<<<512 / 16, 64, 0, stream>>>(zp, W2, b2, out);
    } else {
        lstm2_mono<<<512, 512, 0, stream>>>(x, W1, b1, W2, b2, out);
    }
}